// Round 6
// baseline (895.993 us; speedup 1.0000x reference)
//
#include <hip/hip_runtime.h>
#include <math.h>

namespace {
constexpr int kB = 8, kNG = 5, kNL = 75, kNF = 196, kC = 640;
constexpr int kNTokL = kNL * kNF;      // 14700
constexpr int kNTot = kNG + kNTokL;    // 14705
constexpr float kEps = 1e-12f;
constexpr float kInvAlpha = 10.0f;
constexpr int kKC = 20;                // 640 / 32 K-chunks
constexpr int kTiles = 230;            // 64-token tiles per batch
constexpr int kNT = 5;                 // 16-d tiles per wave (wave = 64 tok x 80 d)
}

typedef __attribute__((ext_vector_type(8))) short short8;
typedef __attribute__((ext_vector_type(4))) float floatx4;

union S8U { short8 v; ushort u[8]; };

// round-to-nearest-even bf16 split: x ~= hi + lo
__device__ __forceinline__ void bsplit(float x, ushort& h, ushort& l) {
  union { float f; uint u; } a; a.f = x;
  uint uh = (a.u + 0x7FFFu + ((a.u >> 16) & 1u)) >> 16;
  h = (ushort)uh;
  union { uint u; float f; } bb; bb.u = uh << 16;
  float r = x - bb.f;
  union { float f; uint u; } c; c.f = r;
  l = (ushort)((c.u + 0x7FFFu + ((c.u >> 16) & 1u)) >> 16);
}

#define MFMA_BF16(a, b, c) __builtin_amdgcn_mfma_f32_16x16x32_bf16(a, b, c, 0, 0, 0)

// barrier that does NOT drain vmcnt (keeps global prefetches in flight)
__device__ __forceinline__ void bar_lds() {
  asm volatile("s_waitcnt lgkmcnt(0)\n\ts_barrier" ::: "memory");
}

// ---------- small kernels ----------

// s_l[b,c] = sum_t local_f[b,t,c]. grid (8,128), block 320.
__global__ void k_sum_local(const float* __restrict__ lf, float* __restrict__ s_l) {
  const int b = blockIdx.x, slice = blockIdx.y;
  const int tid = threadIdx.x;
  const int c4 = tid % 160, h = tid / 160;
  const int t0 = slice * 115 + (h ? 58 : 0);
  const int t1 = min(slice * 115 + (h ? 115 : 58), kNTokL);
  const float* p = lf + ((size_t)b * kNTokL + t0) * kC + c4 * 4;
  float4 acc = {0.f, 0.f, 0.f, 0.f};
  for (int t = t0; t < t1; ++t) {
    const float4 v = *(const float4*)p;
    p += kC;
    acc.x += v.x; acc.y += v.y; acc.z += v.z; acc.w += v.w;
  }
  float* dst = &s_l[b * kC + c4 * 4];
  atomicAdd(dst + 0, acc.x);
  atomicAdd(dst + 1, acc.y);
  atomicAdd(dst + 2, acc.z);
  atomicAdd(dst + 3, acc.w);
}

// Wk -> Wh/Wl in lane-major MFMA frag tiles: tile (dt,kc) = 512 shorts,
// lane l (l = quad*16 + n) holds W[d = dt*16+n][k = kc*32 + quad*8 .. +8].
__global__ void k_cvtW(const float* __restrict__ Wk, ushort* __restrict__ Wh,
                       ushort* __restrict__ Wl) {
  const int wv = blockIdx.x * 4 + (threadIdx.x >> 6);  // 0..799 = 40 dt x 20 kc
  const int lane = threadIdx.x & 63;
  const int kc = wv % kKC, dt = wv / kKC;
  const int fm = lane & 15, quad = lane >> 4;
  const float* p = Wk + (size_t)(dt * 16 + fm) * kC + kc * 32 + quad * 8;
  float4 a = *(const float4*)p;
  float4 c = *(const float4*)(p + 4);
  S8U h, l;
  bsplit(a.x, h.u[0], l.u[0]); bsplit(a.y, h.u[1], l.u[1]);
  bsplit(a.z, h.u[2], l.u[2]); bsplit(a.w, h.u[3], l.u[3]);
  bsplit(c.x, h.u[4], l.u[4]); bsplit(c.y, h.u[5], l.u[5]);
  bsplit(c.z, h.u[6], l.u[6]); bsplit(c.w, h.u[7], l.u[7]);
  const size_t off = ((size_t)dt * kKC + kc) * 512 + (size_t)lane * 8;
  *(short8*)(Wh + off) = h.v;
  *(short8*)(Wl + off) = l.v;
}

// One wave per (b,d): m[b,d] = (Wq[d]·sum_g gf + Wk[d]·s_l[b]) / 14705
// gc[b,g,d] = Wq[d]·gf[b,g] - m[b,d]
__global__ void k_proj_mean(const float* __restrict__ Wq, const float* __restrict__ Wk,
                            const float* __restrict__ gf, const float* __restrict__ s_l,
                            float* __restrict__ m, float* __restrict__ gc) {
  const int wid = blockIdx.x * 4 + (threadIdx.x >> 6);
  const int lane = threadIdx.x & 63;
  const int b = wid / kC, d = wid % kC;
  float ak = 0.f, ag[kNG] = {0.f, 0.f, 0.f, 0.f, 0.f};
  for (int c = lane; c < kC; c += 64) {
    const float wq = Wq[d * kC + c];
    const float wk = Wk[d * kC + c];
    ak += wk * s_l[b * kC + c];
#pragma unroll
    for (int g = 0; g < kNG; ++g) ag[g] += wq * gf[(b * kNG + g) * kC + c];
  }
#pragma unroll
  for (int off = 32; off > 0; off >>= 1) {
    ak += __shfl_xor(ak, off);
#pragma unroll
    for (int g = 0; g < kNG; ++g) ag[g] += __shfl_xor(ag[g], off);
  }
  if (lane == 0) {
    float aq = 0.f;
#pragma unroll
    for (int g = 0; g < kNG; ++g) aq += ag[g];
    const float mv = (aq + ak) / (float)kNTot;
    m[b * kC + d] = mv;
#pragma unroll
    for (int g = 0; g < kNG; ++g) gc[(b * kNG + g) * kC + d] = ag[g] - mv;
  }
}

__global__ void k_norm_g(const float* __restrict__ gc, float* __restrict__ gn) {
  const int row = blockIdx.x;
  __shared__ float red[256];
  float a = 0.f;
  for (int d = threadIdx.x; d < kC; d += 256) {
    const float v = gc[row * kC + d];
    a += v * v;
  }
  red[threadIdx.x] = a;
  __syncthreads();
  for (int s = 128; s > 0; s >>= 1) {
    if (threadIdx.x < s) red[threadIdx.x] += red[threadIdx.x + s];
    __syncthreads();
  }
  const float rs = 1.0f / sqrtf(red[0] + kEps);
  for (int d = threadIdx.x; d < kC; d += 256) gn[row * kC + d] = gc[row * kC + d] * rs;
}

// ---------- the big fused kernel ----------
// Block = 64 tokens x ALL 640 d. 8 waves, wave wn = 64 tok x 80 d (5 nt tiles).
// Key change vs R5: MFMA issued in 3 PASSES (hh all 20, lh all 20, hl all 20)
// so same-acc updates are 20 MFMAs apart (breaks the back-to-back dependency
// chain that capped MfmaUtil at 36%). Staging: 256 threads write one full
// 16B lane-slot each (conflict-free ds_write_b128).
__global__ __launch_bounds__(512, 1) void k_big(
    const float* __restrict__ lf, const ushort* __restrict__ Wh,
    const ushort* __restrict__ Wl, const float* __restrict__ m,
    const float* __restrict__ gn, float* __restrict__ scores) {
  __shared__ char smem[16384];  // buf p: Ah @ p*8192, Al @ p*8192+4096; red overlays
  ushort* Ah0 = (ushort*)smem;
  ushort* Al0 = (ushort*)(smem + 4096);
  ushort* Ah1 = (ushort*)(smem + 8192);
  ushort* Al1 = (ushort*)(smem + 12288);
  float* red = (float*)smem;  // [8 waves][64 rows][6]

  const int tid = threadIdx.x;
  const int wn = tid >> 6, lane = tid & 63;
  const int fm = lane & 15, quad = lane >> 4;
  const int b = blockIdx.x & 7, tile = blockIdx.x >> 3;
  const int tok0 = tile * 64;

  // staging role (tid < 256): token row sr (0..63), 8-float slot sq (0..3)
  const int sr = tid >> 2, sq = tid & 3;
  const bool stg = tid < 256 && (tok0 + sr) < kNTokL;
  const float* xrow = lf + ((size_t)b * kNTokL + tok0 + sr) * kC + sq * 8;
  // frag slot: tile sr>>4, lane' = sq*16 + (sr&15); 8 shorts at lane'*8
  const int aoff = ((sr >> 4) << 9) + ((sq * 16 + (sr & 15)) << 3);

  const ushort* bhbase = Wh + ((size_t)wn * kNT * kKC) * 512 + (size_t)lane * 8;
  const ushort* blbase = Wl + ((size_t)wn * kNT * kKC) * 512 + (size_t)lane * 8;

  floatx4 acc[4][kNT];
#pragma unroll
  for (int i = 0; i < 4; ++i)
#pragma unroll
    for (int j = 0; j < kNT; ++j) acc[i][j] = (floatx4){0.f, 0.f, 0.f, 0.f};

#define STAGE_A(X0, X1, AH, AL)                               \
  if (stg) {                                                  \
    S8U _h, _l;                                               \
    bsplit((X0).x, _h.u[0], _l.u[0]);                         \
    bsplit((X0).y, _h.u[1], _l.u[1]);                         \
    bsplit((X0).z, _h.u[2], _l.u[2]);                         \
    bsplit((X0).w, _h.u[3], _l.u[3]);                         \
    bsplit((X1).x, _h.u[4], _l.u[4]);                         \
    bsplit((X1).y, _h.u[5], _l.u[5]);                         \
    bsplit((X1).z, _h.u[6], _l.u[6]);                         \
    bsplit((X1).w, _h.u[7], _l.u[7]);                         \
    *(short8*)((AH) + aoff) = _h.v;                           \
    *(short8*)((AL) + aoff) = _l.v;                           \
  }

#define LOADB(BH, BL, KCI)                                                        \
  {                                                                               \
    _Pragma("unroll") for (int nt = 0; nt < kNT; ++nt) {                          \
      BH[nt] = *(const short8*)(bhbase + ((size_t)nt * kKC + (KCI)) * 512);       \
      BL[nt] = *(const short8*)(blbase + ((size_t)nt * kKC + (KCI)) * 512);       \
    }                                                                             \
  }

#define READA(AH, AL)                                                  \
  {                                                                    \
    _Pragma("unroll") for (int mt = 0; mt < 4; ++mt) {                 \
      ah[mt] = *(const short8*)((AH) + mt * 512 + lane * 8);           \
      al[mt] = *(const short8*)((AL) + mt * 512 + lane * 8);           \
    }                                                                  \
  }

// three passes; same-acc re-updates are 20 independent MFMAs apart
#define DOMFMA(BH, BL)                                                 \
  {                                                                    \
    _Pragma("unroll") for (int nt = 0; nt < kNT; ++nt)                 \
        _Pragma("unroll") for (int mt = 0; mt < 4; ++mt)               \
            acc[mt][nt] = MFMA_BF16(ah[mt], BH[nt], acc[mt][nt]);      \
    _Pragma("unroll") for (int nt = 0; nt < kNT; ++nt)                 \
        _Pragma("unroll") for (int mt = 0; mt < 4; ++mt)               \
            acc[mt][nt] = MFMA_BF16(al[mt], BH[nt], acc[mt][nt]);      \
    _Pragma("unroll") for (int nt = 0; nt < kNT; ++nt)                 \
        _Pragma("unroll") for (int mt = 0; mt < 4; ++mt)               \
            acc[mt][nt] = MFMA_BF16(ah[mt], BL[nt], acc[mt][nt]);      \
  }

  const float4 fzero = {0.f, 0.f, 0.f, 0.f};
  float4 x0a = fzero, x0b = fzero, xA0 = fzero, xA1 = fzero, xB0 = fzero, xB1 = fzero;
  if (stg) {
    x0a = *(const float4*)xrow;       x0b = *(const float4*)(xrow + 4);
    xA0 = *(const float4*)(xrow + 32); xA1 = *(const float4*)(xrow + 36);
  }
  STAGE_A(x0a, x0b, Ah0, Al0);
  short8 BH0[kNT], BL0[kNT], BH1[kNT], BL1[kNT];
  LOADB(BH0, BL0, 0);

  short8 ah[4], al[4];
  for (int kc = 0; kc < kKC; kc += 2) {
    // ---- even: compute chunk kc (buf0, BH0) ----
    bar_lds();
    READA(Ah0, Al0);
    LOADB(BH1, BL1, kc + 1);
    if (stg && kc + 2 < kKC) {
      xB0 = *(const float4*)(xrow + (kc + 2) * 32);
      xB1 = *(const float4*)(xrow + (kc + 2) * 32 + 4);
    }
    STAGE_A(xA0, xA1, Ah1, Al1);
    DOMFMA(BH0, BL0);

    // ---- odd: compute chunk kc+1 (buf1, BH1) ----
    bar_lds();
    READA(Ah1, Al1);
    if (kc + 2 < kKC) {
      LOADB(BH0, BL0, kc + 2);
      if (stg && kc + 3 < kKC) {
        xA0 = *(const float4*)(xrow + (kc + 3) * 32);
        xA1 = *(const float4*)(xrow + (kc + 3) * 32 + 4);
      }
      STAGE_A(xB0, xB1, Ah0, Al0);
    }
    DOMFMA(BH1, BL1);
  }

  // ---- epilogue: center, reduce over d, combine 8 waves, write scores ----
  float mv[kNT], gvv[5][kNT];
#pragma unroll
  for (int nt = 0; nt < kNT; ++nt) {
    const int d = wn * 80 + nt * 16 + fm;
    mv[nt] = m[b * kC + d];
#pragma unroll
    for (int g = 0; g < 5; ++g) gvv[g][nt] = gn[(b * kNG + g) * kC + d];
  }

  bar_lds();  // all waves' K-loop ds_reads done before red[] overwrites bufs
#pragma unroll
  for (int mt = 0; mt < 4; ++mt)
#pragma unroll
    for (int reg = 0; reg < 4; ++reg) {
      float part[6] = {0.f, 0.f, 0.f, 0.f, 0.f, 0.f};
#pragma unroll
      for (int nt = 0; nt < kNT; ++nt) {
        const float yc = acc[mt][nt][reg] - mv[nt];
        part[0] += yc * yc;
#pragma unroll
        for (int g = 0; g < 5; ++g) part[1 + g] += yc * gvv[g][nt];
      }
#pragma unroll
      for (int off = 1; off < 16; off <<= 1)
#pragma unroll
        for (int v = 0; v < 6; ++v) part[v] += __shfl_xor(part[v], off);
      if (fm == 0) {
        const int row = mt * 16 + quad * 4 + reg;
#pragma unroll
        for (int v = 0; v < 6; ++v) red[((size_t)wn * 64 + row) * 6 + v] = part[v];
      }
    }
  bar_lds();
  if (tid < 64) {
    const int tok = tok0 + tid;
    if (tok < kNTokL) {
      float s[6] = {0.f, 0.f, 0.f, 0.f, 0.f, 0.f};
#pragma unroll
      for (int w = 0; w < 8; ++w)
#pragma unroll
        for (int v = 0; v < 6; ++v) s[v] += red[((size_t)w * 64 + tid) * 6 + v];
      const float rs = (1.0f / sqrtf(s[0] + kEps)) * kInvAlpha;
      const size_t t = (size_t)b * kNTokL + tok;
#pragma unroll
      for (int g = 0; g < 5; ++g)
        scores[(size_t)g * (kB * kNTokL) + t] = s[1 + g] * rs;
    }
  }
#undef STAGE_A
#undef LOADB
#undef READA
#undef DOMFMA
}

// softmax over f (196) per (b,l,g) row; one wave per row. scores pre-scaled.
__global__ void k_softmax(const float* __restrict__ scores, float* __restrict__ out) {
  const int wid = blockIdx.x * 4 + (threadIdx.x >> 6);
  const int lane = threadIdx.x & 63;
  const int b = wid / (kNL * kNG);
  const int rem = wid % (kNL * kNG);
  const int l = rem / kNG, g = rem % kNG;
  float sv[4];
  float mx = -1e30f;
#pragma unroll
  for (int u = 0; u < 4; ++u) {
    const int f = lane + 64 * u;
    if (f < kNF) {
      const size_t t = (size_t)b * kNTokL + (size_t)l * kNF + f;
      sv[u] = scores[(size_t)g * (kB * kNTokL) + t];
      mx = fmaxf(mx, sv[u]);
    } else {
      sv[u] = 0.f;
    }
  }
#pragma unroll
  for (int off = 32; off > 0; off >>= 1) mx = fmaxf(mx, __shfl_xor(mx, off));
  float se = 0.f;
#pragma unroll
  for (int u = 0; u < 4; ++u) {
    const int f = lane + 64 * u;
    const float e = (f < kNF) ? expf(sv[u] - mx) : 0.f;
    sv[u] = e;
    se += e;
  }
#pragma unroll
  for (int off = 32; off > 0; off >>= 1) se += __shfl_xor(se, off);
  const float inv = 1.0f / se;
#pragma unroll
  for (int u = 0; u < 4; ++u) {
    const int f = lane + 64 * u;
    if (f < kNF) out[((size_t)(b * kNL + l) * kNG + g) * kNF + f] = sv[u] * inv;
  }
}

// ===================== launcher =====================

extern "C" void kernel_launch(void* const* d_in, const int* in_sizes, int n_in,
                              void* d_out, int out_size, void* d_ws, size_t ws_size,
                              hipStream_t stream) {
  (void)in_sizes; (void)n_in; (void)out_size; (void)ws_size;
  const float* gf = (const float*)d_in[0];  // [8,5,640]
  const float* lf = (const float*)d_in[1];  // [8,75,196,640]
  const float* Wq = (const float*)d_in[2];  // [640,640]
  const float* Wk = (const float*)d_in[3];  // [640,640]
  float* ws = (float*)d_ws;
  float* out = (float*)d_out;

  // workspace (float offsets): total ~4.2 MB
  float* s_l    = ws;            // 5120
  float* m      = ws + 5120;     // 5120
  float* gc     = ws + 10240;    // 25600
  float* gn     = ws + 35840;    // 25600
  float* scores = ws + 61440;    // 5*117600 = 588000  (layout [g][t])
  ushort* Wh    = (ushort*)(ws + 649440);  // 409600 shorts
  ushort* Wl    = (ushort*)(ws + 854240);  // 409600 shorts

  hipMemsetAsync(s_l, 0, (size_t)5120 * 4, stream);

  k_sum_local<<<dim3(kB, 128), 320, 0, stream>>>(lf, s_l);
  k_cvtW<<<200, 256, 0, stream>>>(Wk, Wh, Wl);
  k_proj_mean<<<(kB * kC) / 4, 256, 0, stream>>>(Wq, Wk, gf, s_l, m, gc);
  k_norm_g<<<kB * kNG, 256, 0, stream>>>(gc, gn);
  k_big<<<kTiles * kB, 512, 0, stream>>>(lf, Wh, Wl, m, gn, scores);
  k_softmax<<<750, 256, 0, stream>>>(scores, out);
}